// Round 1
// baseline (2217.718 us; speedup 1.0000x reference)
//
#include <hip/hip_runtime.h>

#define N_NODES 50000
#define N_EDGES 800000
#define NFEAT 512
#define NHID 128
#define NCLASS 64

// ---------------- fp32 tiled GEMM: C[M,N] = A[M,K] @ B[K,N] ----------------
// BM=64, BN=64, BK=16, 256 threads, 4x4 microtile per thread.
template<int K, int N>
__global__ __launch_bounds__(256) void gemm_tiled(const float* __restrict__ A,
                                                  const float* __restrict__ B,
                                                  float* __restrict__ C, int M)
{
    const int BM = 64, BN = 64, BK = 16;
    __shared__ float As[BK][BM + 1];
    __shared__ float Bs[BK][BN + 1];
    const int tid = threadIdx.x;
    const int tx = tid & 15, ty = tid >> 4;
    const int m0 = blockIdx.x * BM;
    const int n0 = blockIdx.y * BN;

    float acc[4][4] = {};

    // loader indices
    const int la_m = tid >> 2;        // 0..63
    const int la_k = (tid & 3) * 4;   // 0,4,8,12
    const int lb_k = tid >> 4;        // 0..15
    const int lb_n = (tid & 15) * 4;  // 0..60

    for (int k0 = 0; k0 < K; k0 += BK) {
        float4 av = make_float4(0.f, 0.f, 0.f, 0.f);
        const int am = m0 + la_m;
        if (am < M) av = *(const float4*)&A[(long long)am * K + k0 + la_k];
        As[la_k + 0][la_m] = av.x;
        As[la_k + 1][la_m] = av.y;
        As[la_k + 2][la_m] = av.z;
        As[la_k + 3][la_m] = av.w;

        const float4 bv = *(const float4*)&B[(long long)(k0 + lb_k) * N + n0 + lb_n];
        Bs[lb_k][lb_n + 0] = bv.x;
        Bs[lb_k][lb_n + 1] = bv.y;
        Bs[lb_k][lb_n + 2] = bv.z;
        Bs[lb_k][lb_n + 3] = bv.w;
        __syncthreads();

        #pragma unroll
        for (int kk = 0; kk < BK; ++kk) {
            float a[4], b[4];
            #pragma unroll
            for (int i = 0; i < 4; ++i) a[i] = As[kk][ty * 4 + i];
            #pragma unroll
            for (int j = 0; j < 4; ++j) b[j] = Bs[kk][tx * 4 + j];
            #pragma unroll
            for (int i = 0; i < 4; ++i)
                #pragma unroll
                for (int j = 0; j < 4; ++j)
                    acc[i][j] += a[i] * b[j];
        }
        __syncthreads();
    }

    #pragma unroll
    for (int i = 0; i < 4; ++i) {
        const int m = m0 + ty * 4 + i;
        if (m >= M) continue;
        float4 o = make_float4(acc[i][0], acc[i][1], acc[i][2], acc[i][3]);
        *(float4*)&C[(long long)m * N + n0 + tx * 4] = o;
    }
}

// ---------------- zero a float buffer (as float4) ----------------
__global__ void zero_kernel(float4* __restrict__ p, int n4)
{
    int i = blockIdx.x * blockDim.x + threadIdx.x;
    int stride = gridDim.x * blockDim.x;
    for (; i < n4; i += stride) p[i] = make_float4(0.f, 0.f, 0.f, 0.f);
}

// ---------------- SpMM (COO, edge-parallel, float atomics) ----------------
// out[row[e], :] += val[e] * feat[col[e], :]
// D/4 threads per edge; each thread does a float4 gather + 4 atomicAdds.
template<int D>
__global__ void spmm_atomic(const float* __restrict__ feat,
                            const int* __restrict__ erow,
                            const int* __restrict__ ecol,
                            const float* __restrict__ eval_,
                            float* __restrict__ out)
{
    const int TPE = D / 4;
    int t = blockIdx.x * blockDim.x + threadIdx.x;
    int e = t / TPE;
    if (e >= N_EDGES) return;
    const int f4 = (t % TPE) * 4;
    const int r = erow[e];
    const int c = ecol[e];
    const float v = eval_[e];
    const float4 xv = *(const float4*)&feat[(long long)c * D + f4];
    float* o = &out[(long long)r * D + f4];
    atomicAdd(o + 0, v * xv.x);
    atomicAdd(o + 1, v * xv.y);
    atomicAdd(o + 2, v * xv.z);
    atomicAdd(o + 3, v * xv.w);
}

// ---------------- bias + relu in place over [N_NODES, NHID] ----------------
__global__ void bias_relu_kernel(float* __restrict__ h, const float* __restrict__ b)
{
    const int total = N_NODES * NHID / 4;
    int i = blockIdx.x * blockDim.x + threadIdx.x;
    if (i >= total) return;
    const int colq = i & (NHID / 4 - 1);
    float4 v = ((float4*)h)[i];
    const float4 bb = ((const float4*)b)[colq];
    v.x = fmaxf(v.x + bb.x, 0.f);
    v.y = fmaxf(v.y + bb.y, 0.f);
    v.z = fmaxf(v.z + bb.z, 0.f);
    v.w = fmaxf(v.w + bb.w, 0.f);
    ((float4*)h)[i] = v;
}

// ---------------- init out with bias b2 broadcast ----------------
__global__ void init_out_kernel(float* __restrict__ out, const float* __restrict__ b2)
{
    const int total = N_NODES * NCLASS / 4;
    int i = blockIdx.x * blockDim.x + threadIdx.x;
    if (i >= total) return;
    const int colq = i & (NCLASS / 4 - 1);
    ((float4*)out)[i] = ((const float4*)b2)[colq];
}

extern "C" void kernel_launch(void* const* d_in, const int* in_sizes, int n_in,
                              void* d_out, int out_size, void* d_ws, size_t ws_size,
                              hipStream_t stream)
{
    const float* x  = (const float*)d_in[0];
    const float* W1 = (const float*)d_in[1];
    const float* b1 = (const float*)d_in[2];
    const float* W2 = (const float*)d_in[3];
    const float* b2 = (const float*)d_in[4];
    const float* ev = (const float*)d_in[5];
    const int*   er = (const int*)d_in[6];
    const int*   ec = (const int*)d_in[7];
    float* out = (float*)d_out;

    float* XW1  = (float*)d_ws;                          // [N_NODES, NHID]  25.6 MB
    float* Hpre = XW1 + (size_t)N_NODES * NHID;          // [N_NODES, NHID]  25.6 MB
    float* HW2  = XW1;                                   // [N_NODES, NCLASS] reuses XW1 slot

    // 1) XW1 = x @ W1
    {
        dim3 grid((N_NODES + 63) / 64, NHID / 64);
        gemm_tiled<NFEAT, NHID><<<grid, 256, 0, stream>>>(x, W1, XW1, N_NODES);
    }
    // 2) Hpre = 0
    {
        const int n4 = N_NODES * NHID / 4;
        zero_kernel<<<2048, 256, 0, stream>>>((float4*)Hpre, n4);
    }
    // 3) Hpre += scatter(adj @ XW1)
    {
        const int threads = N_EDGES * (NHID / 4);
        spmm_atomic<NHID><<<(threads + 255) / 256, 256, 0, stream>>>(XW1, er, ec, ev, Hpre);
    }
    // 4) Hpre = relu(Hpre + b1)
    {
        const int n4 = N_NODES * NHID / 4;
        bias_relu_kernel<<<(n4 + 255) / 256, 256, 0, stream>>>(Hpre, b1);
    }
    // 5) HW2 = Hpre @ W2
    {
        dim3 grid((N_NODES + 63) / 64, NCLASS / 64);
        gemm_tiled<NHID, NCLASS><<<grid, 256, 0, stream>>>(Hpre, W2, HW2, N_NODES);
    }
    // 6) out = b2 (broadcast)
    {
        const int n4 = N_NODES * NCLASS / 4;
        init_out_kernel<<<(n4 + 255) / 256, 256, 0, stream>>>(out, b2);
    }
    // 7) out += scatter(adj @ HW2)
    {
        const int threads = N_EDGES * (NCLASS / 4);
        spmm_atomic<NCLASS><<<(threads + 255) / 256, 256, 0, stream>>>(HW2, er, ec, ev, out);
    }
}

// Round 2
// 521.029 us; speedup vs baseline: 4.2564x; 4.2564x over previous
//
#include <hip/hip_runtime.h>

#define N_NODES 50000
#define N_EDGES 800000
#define NFEAT 512
#define NHID 128
#define NCLASS 64

// ---------------- fp32 tiled GEMM: C[M,N] = A[M,K] @ B[K,N] ----------------
// BM=64, BN=64, BK=16, 256 threads, 4x4 microtile per thread.
template<int K, int N>
__global__ __launch_bounds__(256) void gemm_tiled(const float* __restrict__ A,
                                                  const float* __restrict__ B,
                                                  float* __restrict__ C, int M)
{
    const int BM = 64, BN = 64, BK = 16;
    __shared__ float As[BK][BM + 1];
    __shared__ float Bs[BK][BN + 1];
    const int tid = threadIdx.x;
    const int tx = tid & 15, ty = tid >> 4;
    const int m0 = blockIdx.x * BM;
    const int n0 = blockIdx.y * BN;

    float acc[4][4] = {};

    const int la_m = tid >> 2;        // 0..63
    const int la_k = (tid & 3) * 4;   // 0,4,8,12
    const int lb_k = tid >> 4;        // 0..15
    const int lb_n = (tid & 15) * 4;  // 0..60

    for (int k0 = 0; k0 < K; k0 += BK) {
        float4 av = make_float4(0.f, 0.f, 0.f, 0.f);
        const int am = m0 + la_m;
        if (am < M) av = *(const float4*)&A[(long long)am * K + k0 + la_k];
        As[la_k + 0][la_m] = av.x;
        As[la_k + 1][la_m] = av.y;
        As[la_k + 2][la_m] = av.z;
        As[la_k + 3][la_m] = av.w;

        const float4 bv = *(const float4*)&B[(long long)(k0 + lb_k) * N + n0 + lb_n];
        Bs[lb_k][lb_n + 0] = bv.x;
        Bs[lb_k][lb_n + 1] = bv.y;
        Bs[lb_k][lb_n + 2] = bv.z;
        Bs[lb_k][lb_n + 3] = bv.w;
        __syncthreads();

        #pragma unroll
        for (int kk = 0; kk < BK; ++kk) {
            float a[4], b[4];
            #pragma unroll
            for (int i = 0; i < 4; ++i) a[i] = As[kk][ty * 4 + i];
            #pragma unroll
            for (int j = 0; j < 4; ++j) b[j] = Bs[kk][tx * 4 + j];
            #pragma unroll
            for (int i = 0; i < 4; ++i)
                #pragma unroll
                for (int j = 0; j < 4; ++j)
                    acc[i][j] += a[i] * b[j];
        }
        __syncthreads();
    }

    #pragma unroll
    for (int i = 0; i < 4; ++i) {
        const int m = m0 + ty * 4 + i;
        if (m >= M) continue;
        float4 o = make_float4(acc[i][0], acc[i][1], acc[i][2], acc[i][3]);
        *(float4*)&C[(long long)m * N + n0 + tx * 4] = o;
    }
}

// ---------------- small helpers ----------------
__global__ void zero_int_kernel(int* __restrict__ p, int n)
{
    int i = blockIdx.x * blockDim.x + threadIdx.x;
    int stride = gridDim.x * blockDim.x;
    for (; i < n; i += stride) p[i] = 0;
}

// ---------------- CSR build ----------------
__global__ void hist_kernel(const int* __restrict__ er, int* __restrict__ counts)
{
    int e = blockIdx.x * blockDim.x + threadIdx.x;
    if (e < N_EDGES) atomicAdd(&counts[er[e]], 1);
}

// single-block exclusive scan of counts[N_NODES] -> row_ptr[N_NODES+1]
__global__ __launch_bounds__(1024) void scan_kernel(const int* __restrict__ counts,
                                                    int* __restrict__ row_ptr)
{
    __shared__ int part[1024];
    const int tid = threadIdx.x;
    const int CH = (N_NODES + 1023) / 1024;   // 49
    const int base = tid * CH;
    int s = 0;
    for (int i = 0; i < CH; ++i) {
        int idx = base + i;
        if (idx < N_NODES) s += counts[idx];
    }
    part[tid] = s;
    __syncthreads();
    // Kogge-Stone inclusive scan
    for (int off = 1; off < 1024; off <<= 1) {
        int v = 0;
        if (tid >= off) v = part[tid - off];
        __syncthreads();
        part[tid] += v;
        __syncthreads();
    }
    int prefix = (tid == 0) ? 0 : part[tid - 1];
    for (int i = 0; i < CH; ++i) {
        int idx = base + i;
        if (idx < N_NODES) {
            row_ptr[idx] = prefix;
            prefix += counts[idx];
        }
    }
    if (tid == 1023) row_ptr[N_NODES] = part[1023];
}

__global__ void scatter_kernel(const int* __restrict__ er, const int* __restrict__ ec,
                               const float* __restrict__ ev,
                               const int* __restrict__ row_ptr, int* __restrict__ fill,
                               int* __restrict__ cols, float* __restrict__ vals)
{
    int e = blockIdx.x * blockDim.x + threadIdx.x;
    if (e >= N_EDGES) return;
    const int r = er[e];
    const int pos = row_ptr[r] + atomicAdd(&fill[r], 1);
    cols[pos] = ec[e];
    vals[pos] = ev[e];
}

// ---------------- CSR SpMM: one wave per row, fused bias (+relu) ----------------
template<int D, bool RELU>
__global__ __launch_bounds__(256) void spmm_csr(const float* __restrict__ feat,
                                                const int* __restrict__ row_ptr,
                                                const int* __restrict__ cols,
                                                const float* __restrict__ vals,
                                                const float* __restrict__ bias,
                                                float* __restrict__ out)
{
    const int wave = blockIdx.x * (blockDim.x >> 6) + (threadIdx.x >> 6);
    const int lane = threadIdx.x & 63;
    if (wave >= N_NODES) return;
    const int r = wave;
    const int beg = row_ptr[r];
    const int end = row_ptr[r + 1];

    if (D == 128) {
        float2 acc = make_float2(0.f, 0.f);
        for (int i = beg; i < end; ++i) {
            const int c = cols[i];
            const float v = vals[i];
            const float2 xv = *(const float2*)&feat[(size_t)c * D + lane * 2];
            acc.x += v * xv.x;
            acc.y += v * xv.y;
        }
        const float2 bb = *(const float2*)&bias[lane * 2];
        acc.x += bb.x;
        acc.y += bb.y;
        if (RELU) {
            acc.x = fmaxf(acc.x, 0.f);
            acc.y = fmaxf(acc.y, 0.f);
        }
        *(float2*)&out[(size_t)r * D + lane * 2] = acc;
    } else {
        float acc = 0.f;
        for (int i = beg; i < end; ++i)
            acc += vals[i] * feat[(size_t)cols[i] * D + lane];
        acc += bias[lane];
        if (RELU) acc = fmaxf(acc, 0.f);
        out[(size_t)r * D + lane] = acc;
    }
}

// ---------------- fallback (atomic) path pieces, used only if ws too small ----
__global__ void zero_kernel(float4* __restrict__ p, int n4)
{
    int i = blockIdx.x * blockDim.x + threadIdx.x;
    int stride = gridDim.x * blockDim.x;
    for (; i < n4; i += stride) p[i] = make_float4(0.f, 0.f, 0.f, 0.f);
}

template<int D>
__global__ void spmm_atomic(const float* __restrict__ feat,
                            const int* __restrict__ erow,
                            const int* __restrict__ ecol,
                            const float* __restrict__ eval_,
                            float* __restrict__ out)
{
    const int TPE = D / 4;
    int t = blockIdx.x * blockDim.x + threadIdx.x;
    int e = t / TPE;
    if (e >= N_EDGES) return;
    const int f4 = (t % TPE) * 4;
    const int r = erow[e];
    const int c = ecol[e];
    const float v = eval_[e];
    const float4 xv = *(const float4*)&feat[(long long)c * D + f4];
    float* o = &out[(long long)r * D + f4];
    atomicAdd(o + 0, v * xv.x);
    atomicAdd(o + 1, v * xv.y);
    atomicAdd(o + 2, v * xv.z);
    atomicAdd(o + 3, v * xv.w);
}

__global__ void bias_relu_kernel(float* __restrict__ h, const float* __restrict__ b)
{
    const int total = N_NODES * NHID / 4;
    int i = blockIdx.x * blockDim.x + threadIdx.x;
    if (i >= total) return;
    const int colq = i & (NHID / 4 - 1);
    float4 v = ((float4*)h)[i];
    const float4 bb = ((const float4*)b)[colq];
    v.x = fmaxf(v.x + bb.x, 0.f);
    v.y = fmaxf(v.y + bb.y, 0.f);
    v.z = fmaxf(v.z + bb.z, 0.f);
    v.w = fmaxf(v.w + bb.w, 0.f);
    ((float4*)h)[i] = v;
}

__global__ void init_out_kernel(float* __restrict__ out, const float* __restrict__ b2)
{
    const int total = N_NODES * NCLASS / 4;
    int i = blockIdx.x * blockDim.x + threadIdx.x;
    if (i >= total) return;
    const int colq = i & (NCLASS / 4 - 1);
    ((float4*)out)[i] = ((const float4*)b2)[colq];
}

extern "C" void kernel_launch(void* const* d_in, const int* in_sizes, int n_in,
                              void* d_out, int out_size, void* d_ws, size_t ws_size,
                              hipStream_t stream)
{
    const float* x  = (const float*)d_in[0];
    const float* W1 = (const float*)d_in[1];
    const float* b1 = (const float*)d_in[2];
    const float* W2 = (const float*)d_in[3];
    const float* b2 = (const float*)d_in[4];
    const float* ev = (const float*)d_in[5];
    const int*   er = (const int*)d_in[6];
    const int*   ec = (const int*)d_in[7];
    float* out = (float*)d_out;

    // workspace layout (all 4-byte elements)
    float* XW1  = (float*)d_ws;                       // 6,400,000 f
    float* Hpre = XW1 + (size_t)N_NODES * NHID;       // 6,400,000 f
    int* row_ptr = (int*)(Hpre + (size_t)N_NODES * NHID);  // 50016
    int* fill    = row_ptr + 50016;                   // 50016
    int* counts  = fill + 50016;                      // 50016
    int* cols    = counts + 50016;                    // 800,000
    float* vals  = (float*)(cols + N_EDGES);          // 800,000
    const size_t needed = ((size_t)N_NODES * NHID * 2 + 50016 * 3 + (size_t)N_EDGES * 2) * 4;

    float* HW2 = XW1;  // [N_NODES, NCLASS] reuses XW1 slot after GEMM2 input read

    if (ws_size >= needed) {
        // ---- CSR build ----
        zero_int_kernel<<<128, 256, 0, stream>>>(row_ptr, 50016 * 3);  // row_ptr,fill,counts
        hist_kernel<<<(N_EDGES + 255) / 256, 256, 0, stream>>>(er, counts);
        scan_kernel<<<1, 1024, 0, stream>>>(counts, row_ptr);
        scatter_kernel<<<(N_EDGES + 255) / 256, 256, 0, stream>>>(er, ec, ev, row_ptr, fill, cols, vals);

        // ---- layer 1 ----
        {
            dim3 grid((N_NODES + 63) / 64, NHID / 64);
            gemm_tiled<NFEAT, NHID><<<grid, 256, 0, stream>>>(x, W1, XW1, N_NODES);
        }
        {
            const int blocks = (N_NODES + 3) / 4;   // 4 waves (rows) per 256-thr block
            spmm_csr<NHID, true><<<blocks, 256, 0, stream>>>(XW1, row_ptr, cols, vals, b1, Hpre);
        }
        // ---- layer 2 ----
        {
            dim3 grid((N_NODES + 63) / 64, NCLASS / 64);
            gemm_tiled<NHID, NCLASS><<<grid, 256, 0, stream>>>(Hpre, W2, HW2, N_NODES);
        }
        {
            const int blocks = (N_NODES + 3) / 4;
            spmm_csr<NCLASS, false><<<blocks, 256, 0, stream>>>(HW2, row_ptr, cols, vals, b2, out);
        }
    } else {
        // ---- fallback: previous atomic path ----
        {
            dim3 grid((N_NODES + 63) / 64, NHID / 64);
            gemm_tiled<NFEAT, NHID><<<grid, 256, 0, stream>>>(x, W1, XW1, N_NODES);
        }
        zero_kernel<<<2048, 256, 0, stream>>>((float4*)Hpre, N_NODES * NHID / 4);
        {
            const int threads = N_EDGES * (NHID / 4);
            spmm_atomic<NHID><<<(threads + 255) / 256, 256, 0, stream>>>(XW1, er, ec, ev, Hpre);
        }
        bias_relu_kernel<<<(N_NODES * NHID / 4 + 255) / 256, 256, 0, stream>>>(Hpre, b1);
        {
            dim3 grid((N_NODES + 63) / 64, NCLASS / 64);
            gemm_tiled<NHID, NCLASS><<<grid, 256, 0, stream>>>(Hpre, W2, HW2, N_NODES);
        }
        init_out_kernel<<<(N_NODES * NCLASS / 4 + 255) / 256, 256, 0, stream>>>(out, b2);
        {
            const int threads = N_EDGES * (NCLASS / 4);
            spmm_atomic<NCLASS><<<(threads + 255) / 256, 256, 0, stream>>>(HW2, er, ec, ev, out);
        }
    }
}

// Round 3
// 393.201 us; speedup vs baseline: 5.6402x; 1.3251x over previous
//
#include <hip/hip_runtime.h>

#define N_NODES 50000
#define N_EDGES 800000
#define NFEAT 512
#define NHID 128
#define NCLASS 64

using bf16x8 = __attribute__((ext_vector_type(8))) __bf16;
using f32x4  = __attribute__((ext_vector_type(4))) float;
using u16x8  = __attribute__((ext_vector_type(8))) unsigned short;
using u16x4  = __attribute__((ext_vector_type(4))) unsigned short;

__device__ __forceinline__ unsigned short f2bf(float f)
{
    unsigned u = __builtin_bit_cast(unsigned, f);
    unsigned r = (u + 0x7FFFu + ((u >> 16) & 1u)) >> 16;
    return (unsigned short)r;
}

// ---------------- W transpose + bf16 convert: Wt[n][k] = bf16(W[k][n]) ----------
template<int K, int N>
__global__ void convert_wt(const float* __restrict__ W, unsigned short* __restrict__ Wt)
{
    int idx = blockIdx.x * blockDim.x + threadIdx.x;
    if (idx >= K * N) return;
    int n = idx / K, k = idx % K;
    Wt[idx] = f2bf(W[k * N + n]);
}

// ---------------- split-bf16 MFMA GEMM: C[M,N] = A[M,K] @ B[K,N] ----------------
// A fp32 (split to hi/lo bf16 in LDS), Bt = bf16 [N][K] (pre-transposed).
// BM=128, BN=N (<=128), BK=32, 256 threads = 4 waves, wave w owns rows [32w,32w+32).
template<int K, int N>
__global__ __launch_bounds__(256) void gemm_mfma(const float* __restrict__ A,
                                                 const unsigned short* __restrict__ Bt,
                                                 float* __restrict__ C, int M)
{
    constexpr int BM = 128, BK = 32, NF = N / 16;
    constexpr int LDW = BK + 8;  // +16B pad: row stride 80 B -> <=2-way bank conflicts
    __shared__ unsigned short Ahi[BM][LDW];
    __shared__ unsigned short Alo[BM][LDW];
    __shared__ unsigned short Bs[N][LDW];

    const int tid  = threadIdx.x;
    const int wid  = tid >> 6;
    const int lane = tid & 63;
    const int lm   = lane & 15;
    const int lk   = (lane >> 4) * 8;
    const int m0   = blockIdx.x * BM;

    f32x4 acc[2][NF] = {};

    for (int k0 = 0; k0 < K; k0 += BK) {
        if (k0) __syncthreads();
        // ---- stage A tile (128x32 fp32 -> hi/lo bf16), 16 fp32 per thread ----
        {
            const int r  = tid >> 1;
            const int kc = (tid & 1) * 16;
            const int m  = m0 + r;
            #pragma unroll
            for (int c = 0; c < 4; ++c) {
                float4 f = make_float4(0.f, 0.f, 0.f, 0.f);
                if (m < M) f = *(const float4*)&A[(size_t)m * K + k0 + kc + c * 4];
                u16x4 h, l;
                #pragma unroll
                for (int j = 0; j < 4; ++j) {
                    float v = (&f.x)[j];
                    unsigned short hb = f2bf(v);
                    float hf = __builtin_bit_cast(float, (unsigned)hb << 16);
                    h[j] = hb;
                    l[j] = f2bf(v - hf);
                }
                *(u16x4*)&Ahi[r][kc + c * 4] = h;
                *(u16x4*)&Alo[r][kc + c * 4] = l;
            }
        }
        // ---- stage B tile (N x 32 bf16, already transposed in global) ----
        {
            constexpr int CH  = (N * BK / 8) / 256;  // 8-elem chunks per thread (2 or 1)
            constexpr int CPR = BK / 8;              // chunks per row = 4
            #pragma unroll
            for (int c = 0; c < CH; ++c) {
                const int chunk = tid * CH + c;
                const int n  = chunk / CPR;
                const int kc = (chunk % CPR) * 8;
                u16x8 bv = *(const u16x8*)&Bt[(size_t)n * K + k0 + kc];
                *(u16x8*)&Bs[n][kc] = bv;
            }
        }
        __syncthreads();

        // ---- fragments + MFMA (2 m-frags x NF n-frags x {hi,lo}) ----
        bf16x8 ah[2], al[2];
        #pragma unroll
        for (int mf = 0; mf < 2; ++mf) {
            ah[mf] = __builtin_bit_cast(bf16x8, *(const u16x8*)&Ahi[wid * 32 + mf * 16 + lm][lk]);
            al[mf] = __builtin_bit_cast(bf16x8, *(const u16x8*)&Alo[wid * 32 + mf * 16 + lm][lk]);
        }
        #pragma unroll
        for (int nf = 0; nf < NF; ++nf) {
            bf16x8 b = __builtin_bit_cast(bf16x8, *(const u16x8*)&Bs[nf * 16 + lm][lk]);
            #pragma unroll
            for (int mf = 0; mf < 2; ++mf) {
                acc[mf][nf] = __builtin_amdgcn_mfma_f32_16x16x32_bf16(ah[mf], b, acc[mf][nf], 0, 0, 0);
                acc[mf][nf] = __builtin_amdgcn_mfma_f32_16x16x32_bf16(al[mf], b, acc[mf][nf], 0, 0, 0);
            }
        }
    }

    // ---- epilogue: C/D layout col=lane&15, row=(lane>>4)*4+reg ----
    #pragma unroll
    for (int mf = 0; mf < 2; ++mf) {
        #pragma unroll
        for (int nf = 0; nf < NF; ++nf) {
            #pragma unroll
            for (int r = 0; r < 4; ++r) {
                const int m = m0 + wid * 32 + mf * 16 + (lane >> 4) * 4 + r;
                if (m < M) C[(size_t)m * N + nf * 16 + lm] = acc[mf][nf][r];
            }
        }
    }
}

// ---------------- small helpers ----------------
__global__ void zero_int_kernel(int* __restrict__ p, int n)
{
    int i = blockIdx.x * blockDim.x + threadIdx.x;
    int stride = gridDim.x * blockDim.x;
    for (; i < n; i += stride) p[i] = 0;
}

// ---------------- CSR build ----------------
__global__ void hist_kernel(const int* __restrict__ er, int* __restrict__ counts)
{
    int e = blockIdx.x * blockDim.x + threadIdx.x;
    if (e < N_EDGES) atomicAdd(&counts[er[e]], 1);
}

__global__ __launch_bounds__(1024) void scan_kernel(const int* __restrict__ counts,
                                                    int* __restrict__ row_ptr)
{
    __shared__ int part[1024];
    const int tid = threadIdx.x;
    const int CH = (N_NODES + 1023) / 1024;   // 49
    const int base = tid * CH;
    int s = 0;
    for (int i = 0; i < CH; ++i) {
        int idx = base + i;
        if (idx < N_NODES) s += counts[idx];
    }
    part[tid] = s;
    __syncthreads();
    for (int off = 1; off < 1024; off <<= 1) {
        int v = 0;
        if (tid >= off) v = part[tid - off];
        __syncthreads();
        part[tid] += v;
        __syncthreads();
    }
    int prefix = (tid == 0) ? 0 : part[tid - 1];
    for (int i = 0; i < CH; ++i) {
        int idx = base + i;
        if (idx < N_NODES) {
            row_ptr[idx] = prefix;
            prefix += counts[idx];
        }
    }
    if (tid == 1023) row_ptr[N_NODES] = part[1023];
}

__global__ void scatter_kernel(const int* __restrict__ er, const int* __restrict__ ec,
                               const float* __restrict__ ev,
                               const int* __restrict__ row_ptr, int* __restrict__ fill,
                               int* __restrict__ cols, float* __restrict__ vals)
{
    int e = blockIdx.x * blockDim.x + threadIdx.x;
    if (e >= N_EDGES) return;
    const int r = er[e];
    const int pos = row_ptr[r] + atomicAdd(&fill[r], 1);
    cols[pos] = ec[e];
    vals[pos] = ev[e];
}

// ---------------- CSR SpMM: one wave per row, fused bias (+relu) ----------------
template<int D, bool RELU>
__global__ __launch_bounds__(256) void spmm_csr(const float* __restrict__ feat,
                                                const int* __restrict__ row_ptr,
                                                const int* __restrict__ cols,
                                                const float* __restrict__ vals,
                                                const float* __restrict__ bias,
                                                float* __restrict__ out)
{
    const int wave = blockIdx.x * (blockDim.x >> 6) + (threadIdx.x >> 6);
    const int lane = threadIdx.x & 63;
    if (wave >= N_NODES) return;
    const int r = wave;
    const int beg = row_ptr[r];
    const int end = row_ptr[r + 1];

    if (D == 128) {
        float2 acc = make_float2(0.f, 0.f);
        for (int i = beg; i < end; ++i) {
            const int c = cols[i];
            const float v = vals[i];
            const float2 xv = *(const float2*)&feat[(size_t)c * D + lane * 2];
            acc.x += v * xv.x;
            acc.y += v * xv.y;
        }
        const float2 bb = *(const float2*)&bias[lane * 2];
        acc.x += bb.x;
        acc.y += bb.y;
        if (RELU) {
            acc.x = fmaxf(acc.x, 0.f);
            acc.y = fmaxf(acc.y, 0.f);
        }
        *(float2*)&out[(size_t)r * D + lane * 2] = acc;
    } else {
        float acc = 0.f;
        for (int i = beg; i < end; ++i)
            acc += vals[i] * feat[(size_t)cols[i] * D + lane];
        acc += bias[lane];
        if (RELU) acc = fmaxf(acc, 0.f);
        out[(size_t)r * D + lane] = acc;
    }
}

// ---------------- fallback (atomic) path pieces, used only if ws too small ----
template<int K, int N>
__global__ __launch_bounds__(256) void gemm_tiled(const float* __restrict__ A,
                                                  const float* __restrict__ B,
                                                  float* __restrict__ C, int M)
{
    const int BM = 64, BN = 64, BK = 16;
    __shared__ float As[BK][BM + 1];
    __shared__ float Bs2[BK][BN + 1];
    const int tid = threadIdx.x;
    const int tx = tid & 15, ty = tid >> 4;
    const int m0 = blockIdx.x * BM;
    const int n0 = blockIdx.y * BN;
    float acc[4][4] = {};
    const int la_m = tid >> 2;
    const int la_k = (tid & 3) * 4;
    const int lb_k = tid >> 4;
    const int lb_n = (tid & 15) * 4;
    for (int k0 = 0; k0 < K; k0 += BK) {
        float4 av = make_float4(0.f, 0.f, 0.f, 0.f);
        const int am = m0 + la_m;
        if (am < M) av = *(const float4*)&A[(long long)am * K + k0 + la_k];
        As[la_k + 0][la_m] = av.x;
        As[la_k + 1][la_m] = av.y;
        As[la_k + 2][la_m] = av.z;
        As[la_k + 3][la_m] = av.w;
        const float4 bv = *(const float4*)&B[(long long)(k0 + lb_k) * N + n0 + lb_n];
        Bs2[lb_k][lb_n + 0] = bv.x;
        Bs2[lb_k][lb_n + 1] = bv.y;
        Bs2[lb_k][lb_n + 2] = bv.z;
        Bs2[lb_k][lb_n + 3] = bv.w;
        __syncthreads();
        #pragma unroll
        for (int kk = 0; kk < BK; ++kk) {
            float a[4], b[4];
            #pragma unroll
            for (int i = 0; i < 4; ++i) a[i] = As[kk][ty * 4 + i];
            #pragma unroll
            for (int j = 0; j < 4; ++j) b[j] = Bs2[kk][tx * 4 + j];
            #pragma unroll
            for (int i = 0; i < 4; ++i)
                #pragma unroll
                for (int j = 0; j < 4; ++j)
                    acc[i][j] += a[i] * b[j];
        }
        __syncthreads();
    }
    #pragma unroll
    for (int i = 0; i < 4; ++i) {
        const int m = m0 + ty * 4 + i;
        if (m >= M) continue;
        float4 o = make_float4(acc[i][0], acc[i][1], acc[i][2], acc[i][3]);
        *(float4*)&C[(long long)m * N + n0 + tx * 4] = o;
    }
}

__global__ void zero_kernel(float4* __restrict__ p, int n4)
{
    int i = blockIdx.x * blockDim.x + threadIdx.x;
    int stride = gridDim.x * blockDim.x;
    for (; i < n4; i += stride) p[i] = make_float4(0.f, 0.f, 0.f, 0.f);
}

template<int D>
__global__ void spmm_atomic(const float* __restrict__ feat,
                            const int* __restrict__ erow,
                            const int* __restrict__ ecol,
                            const float* __restrict__ eval_,
                            float* __restrict__ out)
{
    const int TPE = D / 4;
    int t = blockIdx.x * blockDim.x + threadIdx.x;
    int e = t / TPE;
    if (e >= N_EDGES) return;
    const int f4 = (t % TPE) * 4;
    const int r = erow[e];
    const int c = ecol[e];
    const float v = eval_[e];
    const float4 xv = *(const float4*)&feat[(long long)c * D + f4];
    float* o = &out[(long long)r * D + f4];
    atomicAdd(o + 0, v * xv.x);
    atomicAdd(o + 1, v * xv.y);
    atomicAdd(o + 2, v * xv.z);
    atomicAdd(o + 3, v * xv.w);
}

__global__ void bias_relu_kernel(float* __restrict__ h, const float* __restrict__ b)
{
    const int total = N_NODES * NHID / 4;
    int i = blockIdx.x * blockDim.x + threadIdx.x;
    if (i >= total) return;
    const int colq = i & (NHID / 4 - 1);
    float4 v = ((float4*)h)[i];
    const float4 bb = ((const float4*)b)[colq];
    v.x = fmaxf(v.x + bb.x, 0.f);
    v.y = fmaxf(v.y + bb.y, 0.f);
    v.z = fmaxf(v.z + bb.z, 0.f);
    v.w = fmaxf(v.w + bb.w, 0.f);
    ((float4*)h)[i] = v;
}

__global__ void init_out_kernel(float* __restrict__ out, const float* __restrict__ b2)
{
    const int total = N_NODES * NCLASS / 4;
    int i = blockIdx.x * blockDim.x + threadIdx.x;
    if (i >= total) return;
    const int colq = i & (NCLASS / 4 - 1);
    ((float4*)out)[i] = ((const float4*)b2)[colq];
}

extern "C" void kernel_launch(void* const* d_in, const int* in_sizes, int n_in,
                              void* d_out, int out_size, void* d_ws, size_t ws_size,
                              hipStream_t stream)
{
    const float* x  = (const float*)d_in[0];
    const float* W1 = (const float*)d_in[1];
    const float* b1 = (const float*)d_in[2];
    const float* W2 = (const float*)d_in[3];
    const float* b2 = (const float*)d_in[4];
    const float* ev = (const float*)d_in[5];
    const int*   er = (const int*)d_in[6];
    const int*   ec = (const int*)d_in[7];
    float* out = (float*)d_out;

    float* XW1  = (float*)d_ws;                            // 6,400,000 f
    float* Hpre = XW1 + (size_t)N_NODES * NHID;            // 6,400,000 f
    int* row_ptr = (int*)(Hpre + (size_t)N_NODES * NHID);  // 50016
    int* fill    = row_ptr + 50016;
    int* counts  = fill + 50016;
    int* cols    = counts + 50016;                          // 800,000
    float* vals  = (float*)(cols + N_EDGES);                // 800,000
    unsigned short* W1t = (unsigned short*)(vals + N_EDGES);  // 65536 u16
    unsigned short* W2t = W1t + NFEAT * NHID;                 // 8192 u16
    const size_t needed = ((size_t)N_NODES * NHID * 2 + 50016 * 3 + (size_t)N_EDGES * 2) * 4
                        + (NFEAT * NHID + NHID * NCLASS) * 2;

    float* HW2 = XW1;  // [N_NODES, NCLASS] reuses XW1 slot

    if (ws_size >= needed) {
        // ---- CSR build ----
        zero_int_kernel<<<128, 256, 0, stream>>>(row_ptr, 50016 * 3);
        hist_kernel<<<(N_EDGES + 255) / 256, 256, 0, stream>>>(er, counts);
        scan_kernel<<<1, 1024, 0, stream>>>(counts, row_ptr);
        scatter_kernel<<<(N_EDGES + 255) / 256, 256, 0, stream>>>(er, ec, ev, row_ptr, fill, cols, vals);
        // ---- weight preconvert (bf16, transposed) ----
        convert_wt<NFEAT, NHID><<<(NFEAT * NHID + 255) / 256, 256, 0, stream>>>(W1, W1t);
        convert_wt<NHID, NCLASS><<<(NHID * NCLASS + 255) / 256, 256, 0, stream>>>(W2, W2t);

        // ---- layer 1 ----
        gemm_mfma<NFEAT, NHID><<<(N_NODES + 127) / 128, 256, 0, stream>>>(x, W1t, XW1, N_NODES);
        {
            const int blocks = (N_NODES + 3) / 4;
            spmm_csr<NHID, true><<<blocks, 256, 0, stream>>>(XW1, row_ptr, cols, vals, b1, Hpre);
        }
        // ---- layer 2 ----
        gemm_mfma<NHID, NCLASS><<<(N_NODES + 127) / 128, 256, 0, stream>>>(Hpre, W2t, HW2, N_NODES);
        {
            const int blocks = (N_NODES + 3) / 4;
            spmm_csr<NCLASS, false><<<blocks, 256, 0, stream>>>(HW2, row_ptr, cols, vals, b2, out);
        }
    } else {
        // ---- fallback: atomic path (fp32) ----
        {
            dim3 grid((N_NODES + 63) / 64, NHID / 64);
            gemm_tiled<NFEAT, NHID><<<grid, 256, 0, stream>>>(x, W1, XW1, N_NODES);
        }
        zero_kernel<<<2048, 256, 0, stream>>>((float4*)Hpre, N_NODES * NHID / 4);
        {
            const int threads = N_EDGES * (NHID / 4);
            spmm_atomic<NHID><<<(threads + 255) / 256, 256, 0, stream>>>(XW1, er, ec, ev, Hpre);
        }
        bias_relu_kernel<<<(N_NODES * NHID / 4 + 255) / 256, 256, 0, stream>>>(Hpre, b1);
        {
            dim3 grid((N_NODES + 63) / 64, NCLASS / 64);
            gemm_tiled<NHID, NCLASS><<<grid, 256, 0, stream>>>(Hpre, W2, HW2, N_NODES);
        }
        init_out_kernel<<<(N_NODES * NCLASS / 4 + 255) / 256, 256, 0, stream>>>(out, b2);
        {
            const int threads = N_EDGES * (NCLASS / 4);
            spmm_atomic<NCLASS><<<(threads + 255) / 256, 256, 0, stream>>>(HW2, er, ec, ev, out);
        }
    }
}

// Round 4
// 270.577 us; speedup vs baseline: 8.1963x; 1.4532x over previous
//
#include <hip/hip_runtime.h>

#define N_NODES 50000
#define N_EDGES 800000
#define NFEAT 512
#define NHID 128
#define NCLASS 64

#define SCAN_BLOCKS 49   // ceil(50000/1024)

using bf16x8 = __attribute__((ext_vector_type(8))) __bf16;
using f32x4  = __attribute__((ext_vector_type(4))) float;
using u16x8  = __attribute__((ext_vector_type(8))) unsigned short;
using u16x4  = __attribute__((ext_vector_type(4))) unsigned short;

__device__ __forceinline__ unsigned short f2bf(float f)
{
    unsigned u = __builtin_bit_cast(unsigned, f);
    unsigned r = (u + 0x7FFFu + ((u >> 16) & 1u)) >> 16;
    return (unsigned short)r;
}

// ---------------- both weights transpose + bf16 convert, one launch ----------
__global__ void convert_weights(const float* __restrict__ W1, const float* __restrict__ W2,
                                unsigned short* __restrict__ W1t, unsigned short* __restrict__ W2t)
{
    int idx = blockIdx.x * blockDim.x + threadIdx.x;
    if (idx < NFEAT * NHID) {
        int n = idx / NFEAT, k = idx % NFEAT;
        W1t[idx] = f2bf(W1[k * NHID + n]);
    } else {
        int j = idx - NFEAT * NHID;
        if (j < NHID * NCLASS) {
            int n = j / NHID, k = j % NHID;
            W2t[j] = f2bf(W2[k * NCLASS + n]);
        }
    }
}

// ---------------- split-bf16 MFMA GEMM: C[M,N] = A[M,K] @ B[K,N] ----------------
template<int K, int N>
__global__ __launch_bounds__(256) void gemm_mfma(const float* __restrict__ A,
                                                 const unsigned short* __restrict__ Bt,
                                                 float* __restrict__ C, int M)
{
    constexpr int BM = 128, BK = 32, NF = N / 16;
    constexpr int LDW = BK + 8;  // row stride 80 B -> <=2-way bank conflicts (free)
    __shared__ unsigned short Ahi[BM][LDW];
    __shared__ unsigned short Alo[BM][LDW];
    __shared__ unsigned short Bs[N][LDW];

    const int tid  = threadIdx.x;
    const int wid  = tid >> 6;
    const int lane = tid & 63;
    const int lm   = lane & 15;
    const int lk   = (lane >> 4) * 8;
    const int m0   = blockIdx.x * BM;

    f32x4 acc[2][NF] = {};

    for (int k0 = 0; k0 < K; k0 += BK) {
        if (k0) __syncthreads();
        // ---- stage A tile (128x32 fp32 -> hi/lo bf16), 16 fp32 per thread ----
        {
            const int r  = tid >> 1;
            const int kc = (tid & 1) * 16;
            const int m  = m0 + r;
            #pragma unroll
            for (int c = 0; c < 4; ++c) {
                float4 f = make_float4(0.f, 0.f, 0.f, 0.f);
                if (m < M) f = *(const float4*)&A[(size_t)m * K + k0 + kc + c * 4];
                u16x4 h, l;
                #pragma unroll
                for (int j = 0; j < 4; ++j) {
                    float v = (&f.x)[j];
                    unsigned short hb = f2bf(v);
                    float hf = __builtin_bit_cast(float, (unsigned)hb << 16);
                    h[j] = hb;
                    l[j] = f2bf(v - hf);
                }
                *(u16x4*)&Ahi[r][kc + c * 4] = h;
                *(u16x4*)&Alo[r][kc + c * 4] = l;
            }
        }
        // ---- stage B tile (N x 32 bf16, pre-transposed in global) ----
        {
            constexpr int CH  = (N * BK / 8) / 256;
            constexpr int CPR = BK / 8;
            #pragma unroll
            for (int c = 0; c < CH; ++c) {
                const int chunk = tid * CH + c;
                const int n  = chunk / CPR;
                const int kc = (chunk % CPR) * 8;
                u16x8 bv = *(const u16x8*)&Bt[(size_t)n * K + k0 + kc];
                *(u16x8*)&Bs[n][kc] = bv;
            }
        }
        __syncthreads();

        bf16x8 ah[2], al[2];
        #pragma unroll
        for (int mf = 0; mf < 2; ++mf) {
            ah[mf] = __builtin_bit_cast(bf16x8, *(const u16x8*)&Ahi[wid * 32 + mf * 16 + lm][lk]);
            al[mf] = __builtin_bit_cast(bf16x8, *(const u16x8*)&Alo[wid * 32 + mf * 16 + lm][lk]);
        }
        #pragma unroll
        for (int nf = 0; nf < NF; ++nf) {
            bf16x8 b = __builtin_bit_cast(bf16x8, *(const u16x8*)&Bs[nf * 16 + lm][lk]);
            #pragma unroll
            for (int mf = 0; mf < 2; ++mf) {
                acc[mf][nf] = __builtin_amdgcn_mfma_f32_16x16x32_bf16(ah[mf], b, acc[mf][nf], 0, 0, 0);
                acc[mf][nf] = __builtin_amdgcn_mfma_f32_16x16x32_bf16(al[mf], b, acc[mf][nf], 0, 0, 0);
            }
        }
    }

    #pragma unroll
    for (int mf = 0; mf < 2; ++mf) {
        #pragma unroll
        for (int nf = 0; nf < NF; ++nf) {
            #pragma unroll
            for (int r = 0; r < 4; ++r) {
                const int m = m0 + wid * 32 + mf * 16 + (lane >> 4) * 4 + r;
                if (m < M) C[(size_t)m * N + nf * 16 + lm] = acc[mf][nf][r];
            }
        }
    }
}

// ---------------- CSR build ----------------
__global__ void hist_kernel(const int* __restrict__ er, int* __restrict__ counts)
{
    int e = blockIdx.x * blockDim.x + threadIdx.x;
    if (e < N_EDGES) atomicAdd(&counts[er[e]], 1);
}

// phase 1: per-block Kogge-Stone, exclusive partials + block sums
__global__ __launch_bounds__(1024) void scan_blocks(const int* __restrict__ counts,
                                                    int* __restrict__ row_ptr,
                                                    int* __restrict__ bsums)
{
    __shared__ int tmp[1024];
    const int tid = threadIdx.x;
    const int gid = blockIdx.x * 1024 + tid;
    const int v = (gid < N_NODES) ? counts[gid] : 0;
    tmp[tid] = v;
    __syncthreads();
    #pragma unroll
    for (int off = 1; off < 1024; off <<= 1) {
        int t = (tid >= off) ? tmp[tid - off] : 0;
        __syncthreads();
        tmp[tid] += t;
        __syncthreads();
    }
    if (gid < N_NODES) row_ptr[gid] = tmp[tid] - v;
    if (tid == 1023) bsums[blockIdx.x] = tmp[1023];
}

// phase 2: single-wave exclusive scan of SCAN_BLOCKS sums (in place)
__global__ void scan_bsums(int* __restrict__ bsums)
{
    const int lane = threadIdx.x;  // 64 threads
    const int orig = (lane < SCAN_BLOCKS) ? bsums[lane] : 0;
    int v = orig;
    #pragma unroll
    for (int off = 1; off < 64; off <<= 1) {
        int t = __shfl_up(v, off, 64);
        if (lane >= off) v += t;
    }
    if (lane < SCAN_BLOCKS) bsums[lane] = v - orig;  // exclusive
}

// phase 3: add block offsets; write sentinel
__global__ __launch_bounds__(1024) void add_offsets(int* __restrict__ row_ptr,
                                                    const int* __restrict__ bsums)
{
    const int gid = blockIdx.x * 1024 + threadIdx.x;
    if (gid < N_NODES) row_ptr[gid] += bsums[blockIdx.x];
    if (gid == 0) row_ptr[N_NODES] = N_EDGES;
}

__global__ void scatter_kernel(const int* __restrict__ er, const int* __restrict__ ec,
                               const float* __restrict__ ev,
                               const int* __restrict__ row_ptr, int* __restrict__ fill,
                               int* __restrict__ cols, float* __restrict__ vals)
{
    int e = blockIdx.x * blockDim.x + threadIdx.x;
    if (e >= N_EDGES) return;
    const int r = er[e];
    const int pos = row_ptr[r] + atomicAdd(&fill[r], 1);
    cols[pos] = ec[e];
    vals[pos] = ev[e];
}

// ---------------- CSR SpMM: one wave per row, fused bias (+relu), 2x unroll ----
template<int D, bool RELU>
__global__ __launch_bounds__(256) void spmm_csr(const float* __restrict__ feat,
                                                const int* __restrict__ row_ptr,
                                                const int* __restrict__ cols,
                                                const float* __restrict__ vals,
                                                const float* __restrict__ bias,
                                                float* __restrict__ out)
{
    const int wave = blockIdx.x * (blockDim.x >> 6) + (threadIdx.x >> 6);
    const int lane = threadIdx.x & 63;
    if (wave >= N_NODES) return;
    const int r = wave;
    const int beg = row_ptr[r];
    const int end = row_ptr[r + 1];

    if (D == 128) {
        float2 acc0 = make_float2(0.f, 0.f);
        float2 acc1 = make_float2(0.f, 0.f);
        int i = beg;
        for (; i + 1 < end; i += 2) {
            const int c0 = cols[i],     c1 = cols[i + 1];
            const float v0 = vals[i],   v1 = vals[i + 1];
            const float2 x0 = *(const float2*)&feat[(size_t)c0 * D + lane * 2];
            const float2 x1 = *(const float2*)&feat[(size_t)c1 * D + lane * 2];
            acc0.x += v0 * x0.x; acc0.y += v0 * x0.y;
            acc1.x += v1 * x1.x; acc1.y += v1 * x1.y;
        }
        if (i < end) {
            const int c = cols[i];
            const float v = vals[i];
            const float2 xv = *(const float2*)&feat[(size_t)c * D + lane * 2];
            acc0.x += v * xv.x; acc0.y += v * xv.y;
        }
        const float2 bb = *(const float2*)&bias[lane * 2];
        float2 acc = make_float2(acc0.x + acc1.x + bb.x, acc0.y + acc1.y + bb.y);
        if (RELU) {
            acc.x = fmaxf(acc.x, 0.f);
            acc.y = fmaxf(acc.y, 0.f);
        }
        *(float2*)&out[(size_t)r * D + lane * 2] = acc;
    } else {
        float acc0 = 0.f, acc1 = 0.f;
        int i = beg;
        for (; i + 1 < end; i += 2) {
            acc0 += vals[i]     * feat[(size_t)cols[i]     * D + lane];
            acc1 += vals[i + 1] * feat[(size_t)cols[i + 1] * D + lane];
        }
        if (i < end) acc0 += vals[i] * feat[(size_t)cols[i] * D + lane];
        float acc = acc0 + acc1 + bias[lane];
        if (RELU) acc = fmaxf(acc, 0.f);
        out[(size_t)r * D + lane] = acc;
    }
}

extern "C" void kernel_launch(void* const* d_in, const int* in_sizes, int n_in,
                              void* d_out, int out_size, void* d_ws, size_t ws_size,
                              hipStream_t stream)
{
    const float* x  = (const float*)d_in[0];
    const float* W1 = (const float*)d_in[1];
    const float* b1 = (const float*)d_in[2];
    const float* W2 = (const float*)d_in[3];
    const float* b2 = (const float*)d_in[4];
    const float* ev = (const float*)d_in[5];
    const int*   er = (const int*)d_in[6];
    const int*   ec = (const int*)d_in[7];
    float* out = (float*)d_out;

    float* XW1  = (float*)d_ws;                            // 6,400,000 f
    float* Hpre = XW1 + (size_t)N_NODES * NHID;            // 6,400,000 f
    int* row_ptr = (int*)(Hpre + (size_t)N_NODES * NHID);  // 50016
    int* fill    = row_ptr + 50016;                        // 50016
    int* counts  = fill + 50016;                           // 50016
    int* bsums   = counts + 50016;                         // 64
    int* cols    = bsums + 64;                             // 800,000
    float* vals  = (float*)(cols + N_EDGES);               // 800,000
    unsigned short* W1t = (unsigned short*)(vals + N_EDGES);  // 65536 u16
    unsigned short* W2t = W1t + NFEAT * NHID;                 // 8192 u16

    float* HW2 = XW1;  // [N_NODES, NCLASS] reuses XW1 slot

    // ---- CSR build ----
    hipMemsetAsync(fill, 0, (50016 * 2 + 64) * sizeof(int), stream);  // fill, counts, bsums
    hist_kernel<<<(N_EDGES + 255) / 256, 256, 0, stream>>>(er, counts);
    scan_blocks<<<SCAN_BLOCKS, 1024, 0, stream>>>(counts, row_ptr, bsums);
    scan_bsums<<<1, 64, 0, stream>>>(bsums);
    add_offsets<<<SCAN_BLOCKS, 1024, 0, stream>>>(row_ptr, bsums);
    scatter_kernel<<<(N_EDGES + 255) / 256, 256, 0, stream>>>(er, ec, ev, row_ptr, fill, cols, vals);

    // ---- weight preconvert (bf16, transposed), one launch ----
    {
        const int total = NFEAT * NHID + NHID * NCLASS;
        convert_weights<<<(total + 255) / 256, 256, 0, stream>>>(W1, W2, W1t, W2t);
    }

    // ---- layer 1 ----
    gemm_mfma<NFEAT, NHID><<<(N_NODES + 127) / 128, 256, 0, stream>>>(x, W1t, XW1, N_NODES);
    {
        const int blocks = (N_NODES + 3) / 4;
        spmm_csr<NHID, true><<<blocks, 256, 0, stream>>>(XW1, row_ptr, cols, vals, b1, Hpre);
    }
    // ---- layer 2 ----
    gemm_mfma<NHID, NCLASS><<<(N_NODES + 127) / 128, 256, 0, stream>>>(Hpre, W2t, HW2, N_NODES);
    {
        const int blocks = (N_NODES + 3) / 4;
        spmm_csr<NCLASS, false><<<blocks, 256, 0, stream>>>(HW2, row_ptr, cols, vals, b2, out);
    }
}

// Round 5
// 211.407 us; speedup vs baseline: 10.4903x; 1.2799x over previous
//
#include <hip/hip_runtime.h>

#define N_NODES 50000
#define N_EDGES 800000
#define NFEAT 512
#define NHID 128
#define NCLASS 64

#define SCAN_BLOCKS 49   // ceil(50000/1024)

using bf16x8 = __attribute__((ext_vector_type(8))) __bf16;
using f32x4  = __attribute__((ext_vector_type(4))) float;
using u16x8  = __attribute__((ext_vector_type(8))) unsigned short;
using u16x4  = __attribute__((ext_vector_type(4))) unsigned short;

__device__ __forceinline__ unsigned short f2bf(float f)
{
    unsigned u = __builtin_bit_cast(unsigned, f);
    unsigned r = (u + 0x7FFFu + ((u >> 16) & 1u)) >> 16;
    return (unsigned short)r;
}
__device__ __forceinline__ float bf2f(unsigned short b)
{
    return __builtin_bit_cast(float, (unsigned)b << 16);
}

// ---------------- both weights transpose + bf16 convert, one launch ----------
__global__ void convert_weights(const float* __restrict__ W1, const float* __restrict__ W2,
                                unsigned short* __restrict__ W1t, unsigned short* __restrict__ W2t)
{
    int idx = blockIdx.x * blockDim.x + threadIdx.x;
    if (idx < NFEAT * NHID) {
        int n = idx / NFEAT, k = idx % NFEAT;
        W1t[idx] = f2bf(W1[k * NHID + n]);
    } else {
        int j = idx - NFEAT * NHID;
        if (j < NHID * NCLASS) {
            int n = j / NHID, k = j % NHID;
            W2t[j] = f2bf(W2[k * NCLASS + n]);
        }
    }
}

// ------------- MFMA GEMM, fp32 A (rounded to bf16), bf16 out -----------------
// C_bf16[M,N] = bf16(A[M,K]) @ Bt[N,K]^T.   BM=128, BK=32, 256 thr = 4 waves.
template<int K, int N>
__global__ __launch_bounds__(256) void gemm_mfma_f32a(const float* __restrict__ A,
                                                      const unsigned short* __restrict__ Bt,
                                                      unsigned short* __restrict__ C, int M)
{
    constexpr int BM = 128, BK = 32, NF = N / 16;
    constexpr int LDW = BK + 8;  // row stride 80 B -> <=2-way bank conflicts (free)
    __shared__ unsigned short As[BM][LDW];
    __shared__ unsigned short Bs[N][LDW];

    const int tid  = threadIdx.x;
    const int wid  = tid >> 6;
    const int lane = tid & 63;
    const int lm   = lane & 15;
    const int lk   = (lane >> 4) * 8;
    const int m0   = blockIdx.x * BM;

    f32x4 acc[2][NF] = {};

    for (int k0 = 0; k0 < K; k0 += BK) {
        if (k0) __syncthreads();
        // ---- stage A tile (128x32 fp32 -> bf16), 16 fp32 per thread ----
        {
            const int r  = tid >> 1;
            const int kc = (tid & 1) * 16;
            const int m  = m0 + r;
            #pragma unroll
            for (int c = 0; c < 4; ++c) {
                float4 f = make_float4(0.f, 0.f, 0.f, 0.f);
                if (m < M) f = *(const float4*)&A[(size_t)m * K + k0 + kc + c * 4];
                u16x4 h;
                h[0] = f2bf(f.x); h[1] = f2bf(f.y); h[2] = f2bf(f.z); h[3] = f2bf(f.w);
                *(u16x4*)&As[r][kc + c * 4] = h;
            }
        }
        // ---- stage B tile (N x 32 bf16, pre-transposed in global) ----
        {
            constexpr int CH  = (N * BK / 8) / 256;
            constexpr int CPR = BK / 8;
            #pragma unroll
            for (int c = 0; c < CH; ++c) {
                const int chunk = tid * CH + c;
                const int n  = chunk / CPR;
                const int kc = (chunk % CPR) * 8;
                *(u16x8*)&Bs[n][kc] = *(const u16x8*)&Bt[(size_t)n * K + k0 + kc];
            }
        }
        __syncthreads();

        bf16x8 a[2];
        #pragma unroll
        for (int mf = 0; mf < 2; ++mf)
            a[mf] = __builtin_bit_cast(bf16x8, *(const u16x8*)&As[wid * 32 + mf * 16 + lm][lk]);
        #pragma unroll
        for (int nf = 0; nf < NF; ++nf) {
            bf16x8 b = __builtin_bit_cast(bf16x8, *(const u16x8*)&Bs[nf * 16 + lm][lk]);
            #pragma unroll
            for (int mf = 0; mf < 2; ++mf)
                acc[mf][nf] = __builtin_amdgcn_mfma_f32_16x16x32_bf16(a[mf], b, acc[mf][nf], 0, 0, 0);
        }
    }

    #pragma unroll
    for (int mf = 0; mf < 2; ++mf)
        #pragma unroll
        for (int nf = 0; nf < NF; ++nf)
            #pragma unroll
            for (int r = 0; r < 4; ++r) {
                const int m = m0 + wid * 32 + mf * 16 + (lane >> 4) * 4 + r;
                if (m < M) C[(size_t)m * N + nf * 16 + lm] = f2bf(acc[mf][nf][r]);
            }
}

// ------------- MFMA GEMM, bf16 A, bf16 out -----------------------------------
template<int K, int N>
__global__ __launch_bounds__(256) void gemm_mfma_bf16a(const unsigned short* __restrict__ A,
                                                       const unsigned short* __restrict__ Bt,
                                                       unsigned short* __restrict__ C, int M)
{
    constexpr int BM = 128, BK = 32, NF = N / 16;
    constexpr int LDW = BK + 8;
    __shared__ unsigned short As[BM][LDW];
    __shared__ unsigned short Bs[N][LDW];

    const int tid  = threadIdx.x;
    const int wid  = tid >> 6;
    const int lane = tid & 63;
    const int lm   = lane & 15;
    const int lk   = (lane >> 4) * 8;
    const int m0   = blockIdx.x * BM;

    f32x4 acc[2][NF] = {};

    for (int k0 = 0; k0 < K; k0 += BK) {
        if (k0) __syncthreads();
        // ---- stage A tile (128x32 bf16 direct copy), 2 chunks/thread ----
        {
            #pragma unroll
            for (int c = 0; c < 2; ++c) {
                const int chunk = tid * 2 + c;     // 512 chunks
                const int r  = chunk >> 2;
                const int kc = (chunk & 3) * 8;
                const int m  = m0 + r;
                u16x8 v = {};
                if (m < M) v = *(const u16x8*)&A[(size_t)m * K + k0 + kc];
                *(u16x8*)&As[r][kc] = v;
            }
        }
        // ---- stage B tile ----
        {
            constexpr int CH  = (N * BK / 8) / 256;   // N=64 -> 1
            constexpr int CPR = BK / 8;
            #pragma unroll
            for (int c = 0; c < CH; ++c) {
                const int chunk = tid * CH + c;
                const int n  = chunk / CPR;
                const int kc = (chunk % CPR) * 8;
                *(u16x8*)&Bs[n][kc] = *(const u16x8*)&Bt[(size_t)n * K + k0 + kc];
            }
        }
        __syncthreads();

        bf16x8 a[2];
        #pragma unroll
        for (int mf = 0; mf < 2; ++mf)
            a[mf] = __builtin_bit_cast(bf16x8, *(const u16x8*)&As[wid * 32 + mf * 16 + lm][lk]);
        #pragma unroll
        for (int nf = 0; nf < NF; ++nf) {
            bf16x8 b = __builtin_bit_cast(bf16x8, *(const u16x8*)&Bs[nf * 16 + lm][lk]);
            #pragma unroll
            for (int mf = 0; mf < 2; ++mf)
                acc[mf][nf] = __builtin_amdgcn_mfma_f32_16x16x32_bf16(a[mf], b, acc[mf][nf], 0, 0, 0);
        }
    }

    #pragma unroll
    for (int mf = 0; mf < 2; ++mf)
        #pragma unroll
        for (int nf = 0; nf < NF; ++nf)
            #pragma unroll
            for (int r = 0; r < 4; ++r) {
                const int m = m0 + wid * 32 + mf * 16 + (lane >> 4) * 4 + r;
                if (m < M) C[(size_t)m * N + nf * 16 + lm] = f2bf(acc[mf][nf][r]);
            }
}

// ---------------- CSR build ----------------
__global__ void hist_kernel(const int* __restrict__ er, int* __restrict__ counts)
{
    int e = blockIdx.x * blockDim.x + threadIdx.x;
    if (e < N_EDGES) atomicAdd(&counts[er[e]], 1);
}

__global__ __launch_bounds__(1024) void scan_blocks(const int* __restrict__ counts,
                                                    int* __restrict__ row_ptr,
                                                    int* __restrict__ bsums)
{
    __shared__ int tmp[1024];
    const int tid = threadIdx.x;
    const int gid = blockIdx.x * 1024 + tid;
    const int v = (gid < N_NODES) ? counts[gid] : 0;
    tmp[tid] = v;
    __syncthreads();
    #pragma unroll
    for (int off = 1; off < 1024; off <<= 1) {
        int t = (tid >= off) ? tmp[tid - off] : 0;
        __syncthreads();
        tmp[tid] += t;
        __syncthreads();
    }
    if (gid < N_NODES) row_ptr[gid] = tmp[tid] - v;
    if (tid == 1023) bsums[blockIdx.x] = tmp[1023];
}

__global__ void scan_bsums(int* __restrict__ bsums)
{
    const int lane = threadIdx.x;  // 64 threads
    const int orig = (lane < SCAN_BLOCKS) ? bsums[lane] : 0;
    int v = orig;
    #pragma unroll
    for (int off = 1; off < 64; off <<= 1) {
        int t = __shfl_up(v, off, 64);
        if (lane >= off) v += t;
    }
    if (lane < SCAN_BLOCKS) bsums[lane] = v - orig;  // exclusive
}

__global__ __launch_bounds__(1024) void add_offsets(int* __restrict__ row_ptr,
                                                    const int* __restrict__ bsums)
{
    const int gid = blockIdx.x * 1024 + threadIdx.x;
    if (gid < N_NODES) row_ptr[gid] += bsums[blockIdx.x];
    if (gid == 0) row_ptr[N_NODES] = N_EDGES;
}

__global__ void scatter_kernel(const int* __restrict__ er, const int* __restrict__ ec,
                               const float* __restrict__ ev,
                               const int* __restrict__ row_ptr, int* __restrict__ fill,
                               int* __restrict__ cols, float* __restrict__ vals)
{
    int e = blockIdx.x * blockDim.x + threadIdx.x;
    if (e >= N_EDGES) return;
    const int r = er[e];
    const int pos = row_ptr[r] + atomicAdd(&fill[r], 1);
    cols[pos] = ec[e];
    vals[pos] = ev[e];
}

// ---- SpMM1: bf16 feat [*,128] gather, fp32 acc, +bias, relu, bf16 out -------
__global__ __launch_bounds__(256) void spmm_bf16_h(const unsigned short* __restrict__ feat,
                                                   const int* __restrict__ row_ptr,
                                                   const int* __restrict__ cols,
                                                   const float* __restrict__ vals,
                                                   const float* __restrict__ bias,
                                                   unsigned short* __restrict__ out)
{
    const int wave = blockIdx.x * (blockDim.x >> 6) + (threadIdx.x >> 6);
    const int lane = threadIdx.x & 63;
    if (wave >= N_NODES) return;
    const int beg = row_ptr[wave];
    const int end = row_ptr[wave + 1];

    float ax[4] = {}, ay[4] = {};
    int i = beg;
    for (; i + 3 < end; i += 4) {
        #pragma unroll
        for (int u = 0; u < 4; ++u) {
            const int c = cols[i + u];
            const float v = vals[i + u];
            const unsigned w = *(const unsigned*)&feat[(size_t)c * NHID + lane * 2];
            ax[u] += v * bf2f((unsigned short)(w & 0xFFFF));
            ay[u] += v * bf2f((unsigned short)(w >> 16));
        }
    }
    for (; i < end; ++i) {
        const int c = cols[i];
        const float v = vals[i];
        const unsigned w = *(const unsigned*)&feat[(size_t)c * NHID + lane * 2];
        ax[0] += v * bf2f((unsigned short)(w & 0xFFFF));
        ay[0] += v * bf2f((unsigned short)(w >> 16));
    }
    const float2 bb = *(const float2*)&bias[lane * 2];
    float rx = fmaxf(ax[0] + ax[1] + ax[2] + ax[3] + bb.x, 0.f);
    float ry = fmaxf(ay[0] + ay[1] + ay[2] + ay[3] + bb.y, 0.f);
    unsigned pack = (unsigned)f2bf(rx) | ((unsigned)f2bf(ry) << 16);
    *(unsigned*)&out[(size_t)wave * NHID + lane * 2] = pack;
}

// ---- SpMM2: bf16 feat [*,64] gather, fp32 acc, +bias, fp32 out --------------
__global__ __launch_bounds__(256) void spmm_bf16_o(const unsigned short* __restrict__ feat,
                                                   const int* __restrict__ row_ptr,
                                                   const int* __restrict__ cols,
                                                   const float* __restrict__ vals,
                                                   const float* __restrict__ bias,
                                                   float* __restrict__ out)
{
    const int wave = blockIdx.x * (blockDim.x >> 6) + (threadIdx.x >> 6);
    const int lane = threadIdx.x & 63;
    if (wave >= N_NODES) return;
    const int beg = row_ptr[wave];
    const int end = row_ptr[wave + 1];

    float a[4] = {};
    int i = beg;
    for (; i + 3 < end; i += 4) {
        #pragma unroll
        for (int u = 0; u < 4; ++u)
            a[u] += vals[i + u] * bf2f(feat[(size_t)cols[i + u] * NCLASS + lane]);
    }
    for (; i < end; ++i)
        a[0] += vals[i] * bf2f(feat[(size_t)cols[i] * NCLASS + lane]);
    out[(size_t)wave * NCLASS + lane] = a[0] + a[1] + a[2] + a[3] + bias[lane];
}

extern "C" void kernel_launch(void* const* d_in, const int* in_sizes, int n_in,
                              void* d_out, int out_size, void* d_ws, size_t ws_size,
                              hipStream_t stream)
{
    const float* x  = (const float*)d_in[0];
    const float* W1 = (const float*)d_in[1];
    const float* b1 = (const float*)d_in[2];
    const float* W2 = (const float*)d_in[3];
    const float* b2 = (const float*)d_in[4];
    const float* ev = (const float*)d_in[5];
    const int*   er = (const int*)d_in[6];
    const int*   ec = (const int*)d_in[7];
    float* out = (float*)d_out;

    unsigned short* XW1  = (unsigned short*)d_ws;            // 6,400,000 u16 (bf16)
    unsigned short* Hpre = XW1 + (size_t)N_NODES * NHID;     // 6,400,000 u16
    int* row_ptr = (int*)(Hpre + (size_t)N_NODES * NHID);    // 50016
    int* fill    = row_ptr + 50016;                          // 50016
    int* counts  = fill + 50016;                             // 50016
    int* bsums   = counts + 50016;                           // 64
    int* cols    = bsums + 64;                               // 800,000
    float* vals  = (float*)(cols + N_EDGES);                 // 800,000
    unsigned short* W1t = (unsigned short*)(vals + N_EDGES); // 65536 u16
    unsigned short* W2t = W1t + NFEAT * NHID;                // 8192 u16

    unsigned short* HW2 = XW1;  // [N_NODES, NCLASS] bf16, reuses XW1 slot

    // ---- CSR build ----
    hipMemsetAsync(fill, 0, (50016 * 2 + 64) * sizeof(int), stream);  // fill, counts, bsums
    hist_kernel<<<(N_EDGES + 255) / 256, 256, 0, stream>>>(er, counts);
    scan_blocks<<<SCAN_BLOCKS, 1024, 0, stream>>>(counts, row_ptr, bsums);
    scan_bsums<<<1, 64, 0, stream>>>(bsums);
    add_offsets<<<SCAN_BLOCKS, 1024, 0, stream>>>(row_ptr, bsums);
    scatter_kernel<<<(N_EDGES + 255) / 256, 256, 0, stream>>>(er, ec, ev, row_ptr, fill, cols, vals);

    // ---- weight preconvert (bf16, transposed), one launch ----
    {
        const int total = NFEAT * NHID + NHID * NCLASS;
        convert_weights<<<(total + 255) / 256, 256, 0, stream>>>(W1, W2, W1t, W2t);
    }

    // ---- layer 1 ----
    gemm_mfma_f32a<NFEAT, NHID><<<(N_NODES + 127) / 128, 256, 0, stream>>>(x, W1t, XW1, N_NODES);
    spmm_bf16_h<<<(N_NODES + 3) / 4, 256, 0, stream>>>(XW1, row_ptr, cols, vals, b1, Hpre);
    // ---- layer 2 ----
    gemm_mfma_bf16a<NHID, NCLASS><<<(N_NODES + 127) / 128, 256, 0, stream>>>(Hpre, W2t, HW2, N_NODES);
    spmm_bf16_o<<<(N_NODES + 3) / 4, 256, 0, stream>>>(HW2, row_ptr, cols, vals, b2, out);
}